// Round 1
// baseline (1099.574 us; speedup 1.0000x reference)
//
#include <hip/hip_runtime.h>
#include <hip/hip_bf16.h>

// ---- problem constants ----
#define N_ROWS 16384   // 8*16*128
#define DIM    256
#define K_CODES 8192

// output layout (flat float32, return order)
#define OFF_ZQ   0
#define OFF_LOSS 4194304
#define OFF_IDX  4194305
#define OFF_CB   4210689
#define OFF_CNT  6307841
#define OFF_MEAN 6316033

// workspace layout (bytes)
#define WS_KEYS   0          // u64[16384] = 131072
#define WS_COUNTS 131072     // f32[8192]  = 32768
#define WS_CNORM  163840     // f32[8192]  = 32768
#define WS_LOSS   196608     // f32
#define WS_N      196612     // f32
#define WS_MEAN   262144     // f32[8192*256] = 8388608
#define WS_NEEDED (262144 + 8388608)

// ---------------- cnorm: ||c_k||^2 in fp64, stored fp32 ----------------
__global__ __launch_bounds__(256) void cnorm_kernel(const float* __restrict__ cb,
                                                    float* __restrict__ cnorm) {
    int wave = threadIdx.x >> 6;
    int lane = threadIdx.x & 63;
    int k = blockIdx.x * 4 + wave;
    const float* row = cb + (size_t)k * DIM;
    float4 v = *(const float4*)(row + lane * 4);
    double s = (double)v.x * v.x + (double)v.y * v.y + (double)v.z * v.z + (double)v.w * v.w;
    #pragma unroll
    for (int off = 32; off; off >>= 1) s += __shfl_down(s, off, 64);
    if (lane == 0) cnorm[k] = (float)s;
}

// ---------------- distance GEMM + argmin ----------------
// block tile: 128 rows x 128 codes, K-chunks of 32; 256 threads, 8x8 per thread.
#define BM 128
#define BN 128
#define BK 32
#define LDA 36  // padded stride in floats (16B-aligned rows)

__global__ __launch_bounds__(256) void dist_kernel(const float* __restrict__ z,
                                                   const float* __restrict__ cb,
                                                   const float* __restrict__ cnorm,
                                                   unsigned long long* __restrict__ keys) {
    __shared__ float As[BM * LDA];
    __shared__ float Bs[BN * LDA];
    const int tid = threadIdx.x;
    const int ty = tid >> 4;   // 0..15 (row group)
    const int tx = tid & 15;   // 0..15 (code group)
    const int rowBase = blockIdx.x * BM;
    const int colBase = blockIdx.y * BN;

    float acc[8][8] = {};

    for (int dk = 0; dk < DIM; dk += BK) {
        // stage: 128 rows x 32 floats each for A and B; 1024 float4 each, 4 per thread
        #pragma unroll
        for (int l = 0; l < 4; ++l) {
            int f = tid + l * 256;
            int r = f >> 3, c4 = (f & 7) * 4;
            float4 va = *(const float4*)(z + (size_t)(rowBase + r) * DIM + dk + c4);
            *(float4*)(As + r * LDA + c4) = va;
            float4 vb = *(const float4*)(cb + (size_t)(colBase + r) * DIM + dk + c4);
            *(float4*)(Bs + r * LDA + c4) = vb;
        }
        __syncthreads();
        #pragma unroll 2
        for (int d4 = 0; d4 < BK; d4 += 4) {
            float4 a[8], b[8];
            #pragma unroll
            for (int i = 0; i < 8; ++i) a[i] = *(const float4*)(As + (i * 16 + ty) * LDA + d4);
            #pragma unroll
            for (int j = 0; j < 8; ++j) b[j] = *(const float4*)(Bs + (j * 16 + tx) * LDA + d4);
            #pragma unroll
            for (int i = 0; i < 8; ++i)
                #pragma unroll
                for (int j = 0; j < 8; ++j) {
                    acc[i][j] = fmaf(a[i].x, b[j].x, acc[i][j]);
                    acc[i][j] = fmaf(a[i].y, b[j].y, acc[i][j]);
                    acc[i][j] = fmaf(a[i].z, b[j].z, acc[i][j]);
                    acc[i][j] = fmaf(a[i].w, b[j].w, acc[i][j]);
                }
        }
        __syncthreads();
    }

    // per-thread best over its 8 codes for each of its 8 rows
    unsigned long long best[8];
    #pragma unroll
    for (int i = 0; i < 8; ++i) {
        unsigned long long bk_ = ~0ull;
        #pragma unroll
        for (int j = 0; j < 8; ++j) {
            int code = colBase + j * 16 + tx;
            float d = cnorm[code] - 2.0f * acc[i][j];
            unsigned u = __float_as_uint(d);
            u ^= ((int)u < 0) ? 0xFFFFFFFFu : 0x80000000u;  // order-preserving encode
            unsigned long long key = ((unsigned long long)u << 32) | (unsigned)code;
            if (key < bk_) bk_ = key;
        }
        best[i] = bk_;
    }

    // cross-thread (tx) reduce via LDS, then one atomic per row
    unsigned long long* red = (unsigned long long*)As;  // 128*16*8 = 16KB <= 18KB
    #pragma unroll
    for (int i = 0; i < 8; ++i) red[(i * 16 + ty) * 16 + tx] = best[i];
    __syncthreads();
    if (tid < BM) {
        unsigned long long m = ~0ull;
        #pragma unroll
        for (int t = 0; t < 16; ++t) {
            unsigned long long v = red[tid * 16 + t];
            if (v < m) m = v;
        }
        atomicMin(keys + rowBase + tid, m);
    }
}

// ---------------- assign: z_q, idx, loss partial, count/mean scatter ----------------
__global__ __launch_bounds__(256) void assign_kernel(const float* __restrict__ z,
                                                     const float* __restrict__ cb,
                                                     const unsigned long long* __restrict__ keys,
                                                     float* __restrict__ zq_out,
                                                     float* __restrict__ idx_out,
                                                     float* __restrict__ counts,
                                                     float* __restrict__ meanAcc,
                                                     float* __restrict__ lossSum) {
    int wave = threadIdx.x >> 6, lane = threadIdx.x & 63;
    int row = blockIdx.x * 4 + wave;
    int idx = (int)(unsigned)(keys[row] & 0xFFFFFFFFull);
    float4 zv = *(const float4*)(z + (size_t)row * DIM + lane * 4);
    float4 cv = *(const float4*)(cb + (size_t)idx * DIM + lane * 4);
    *(float4*)(zq_out + (size_t)row * DIM + lane * 4) = cv;
    float d0 = zv.x - cv.x, d1 = zv.y - cv.y, d2 = zv.z - cv.z, d3 = zv.w - cv.w;
    float ls = d0 * d0 + d1 * d1 + d2 * d2 + d3 * d3;
    #pragma unroll
    for (int off = 32; off; off >>= 1) ls += __shfl_down(ls, off, 64);
    float* m = meanAcc + (size_t)idx * DIM + lane * 4;
    atomicAdd(m + 0, zv.x);
    atomicAdd(m + 1, zv.y);
    atomicAdd(m + 2, zv.z);
    atomicAdd(m + 3, zv.w);
    if (lane == 0) {
        idx_out[row] = (float)idx;
        atomicAdd(counts + idx, 1.0f);
        atomicAdd(lossSum, ls);
    }
}

// ---------------- count finalize + n + loss scalar ----------------
__global__ __launch_bounds__(1024) void count_final_kernel(const float* __restrict__ ema_count,
                                                           const float* __restrict__ counts,
                                                           float* __restrict__ newCount_out,
                                                           float* __restrict__ nOut,
                                                           const float* __restrict__ lossSum,
                                                           float* __restrict__ loss_out) {
    __shared__ float sred[1024];
    const float OMD = (float)(1.0 - 0.99);
    int tid = threadIdx.x;
    float s = 0.f;
    #pragma unroll
    for (int k = tid; k < K_CODES; k += 1024) {
        float nc = 0.99f * ema_count[k] + OMD * counts[k];
        newCount_out[k] = nc;
        s += nc;
    }
    sred[tid] = s;
    __syncthreads();
    for (int off = 512; off; off >>= 1) {
        if (tid < off) sred[tid] += sred[tid + off];
        __syncthreads();
    }
    if (tid == 0) {
        nOut[0] = sred[0];
        loss_out[0] = 1.25f * lossSum[0] / 4194304.0f;
    }
}

// ---------------- mean finalize + new codebook ----------------
__global__ __launch_bounds__(256) void final_kernel(const float* __restrict__ ema_mean,
                                                    const float* __restrict__ meanAcc,
                                                    const float* __restrict__ newCount,
                                                    const float* __restrict__ nPtr,
                                                    float* __restrict__ newMean_out,
                                                    float* __restrict__ newCb_out) {
    const float OMD = (float)(1.0 - 0.99);
    int g = blockIdx.x * 256 + threadIdx.x;   // float4 group id, 0..524287
    int k = g >> 6;
    int c4 = (g & 63) * 4;
    float n = nPtr[0];
    float nc = newCount[k];
    float cs = (nc + 1e-5f) / (n + (float)(K_CODES * 1e-5)) * n;
    size_t base = (size_t)k * DIM + c4;
    float4 em = *(const float4*)(ema_mean + base);
    float4 mm = *(const float4*)(meanAcc + base);
    float4 nm;
    nm.x = 0.99f * em.x + OMD * mm.x;
    nm.y = 0.99f * em.y + OMD * mm.y;
    nm.z = 0.99f * em.z + OMD * mm.z;
    nm.w = 0.99f * em.w + OMD * mm.w;
    *(float4*)(newMean_out + base) = nm;
    float4 cbv;
    cbv.x = nm.x / cs;
    cbv.y = nm.y / cs;
    cbv.z = nm.z / cs;
    cbv.w = nm.w / cs;
    *(float4*)(newCb_out + base) = cbv;
}

extern "C" void kernel_launch(void* const* d_in, const int* in_sizes, int n_in,
                              void* d_out, int out_size, void* d_ws, size_t ws_size,
                              hipStream_t stream) {
    const float* z         = (const float*)d_in[0];
    const float* cb        = (const float*)d_in[1];
    const float* ema_count = (const float*)d_in[2];
    const float* ema_mean  = (const float*)d_in[3];
    float* out = (float*)d_out;
    char* ws = (char*)d_ws;

    unsigned long long* keys = (unsigned long long*)(ws + WS_KEYS);
    float* counts  = (float*)(ws + WS_COUNTS);
    float* cnorm   = (float*)(ws + WS_CNORM);
    float* lossSum = (float*)(ws + WS_LOSS);
    float* nPtr    = (float*)(ws + WS_N);
    float* meanAcc = (float*)(ws + WS_MEAN);

    // init: keys to +inf (all-FF), accumulators to zero — every call (no cross-call state)
    hipMemsetAsync(keys, 0xFF, N_ROWS * 8, stream);
    hipMemsetAsync(ws + WS_COUNTS, 0, WS_NEEDED - WS_COUNTS, stream);

    cnorm_kernel<<<K_CODES / 4, 256, 0, stream>>>(cb, cnorm);
    dist_kernel<<<dim3(N_ROWS / BM, K_CODES / BN), 256, 0, stream>>>(z, cb, cnorm, keys);
    assign_kernel<<<N_ROWS / 4, 256, 0, stream>>>(z, cb, keys, out + OFF_ZQ, out + OFF_IDX,
                                                  counts, meanAcc, lossSum);
    count_final_kernel<<<1, 1024, 0, stream>>>(ema_count, counts, out + OFF_CNT, nPtr,
                                               lossSum, out + OFF_LOSS);
    final_kernel<<<(K_CODES * DIM / 4) / 256, 256, 0, stream>>>(ema_mean, meanAcc,
                                                                out + OFF_CNT, nPtr,
                                                                out + OFF_MEAN, out + OFF_CB);
}

// Round 4
// 524.501 us; speedup vs baseline: 2.0964x; 2.0964x over previous
//
#include <hip/hip_runtime.h>

// ---- problem constants ----
#define N_ROWS 16384   // 8*16*128
#define DIM    256
#define K_CODES 8192

// output layout (flat float32, return order)
#define OFF_ZQ   0
#define OFF_LOSS 4194304
#define OFF_IDX  4194305
#define OFF_CB   4210689
#define OFF_CNT  6307841
#define OFF_MEAN 6316033

// d_out scratch (consumed before the real outputs overwrite these regions):
//   zh [0..2097152) floats, zl [2097152..4194304)   (inside z_q region)
//   ch [4210692..5259268), cl [5259268..6307844)    (inside CB region, 16B aligned)
//   cand u64[16384*64] at float-off 6307844 (byte 25231376, 16B aligned),
//        ends float 8404996 < 8413185. Overlaps CNT/MEAN regions, which are
//        written only AFTER rescore consumed cand (stream-ordered).
#define POFF_ZH   0
#define POFF_ZL   2097152
#define POFF_CH   4210692
#define POFF_CL   5259268
#define POFF_CAND 6307844

// workspace layout (bytes) — proven budget (<= 8.65 MB)
#define WS_KEYS   0          // u64[16384] = 131072 (final chosen code per row)
#define WS_COUNTS 131072     // f32[8192]
#define WS_CNORM  163840     // f32[8192]
#define WS_LOSS   196608     // f32
#define WS_N      196612     // f32
#define WS_MEAN   262144     // f32[8192*256] = 8388608 -> ends 8650752
#define WS_END    8650752

typedef _Float16 half8 __attribute__((ext_vector_type(8)));
typedef float f32x4 __attribute__((ext_vector_type(4)));

// ---------------- fp32 -> fp16 hi/lo planes ----------------
// a ~= hi + lo * 2^-11  (lo pre-scaled by 2048; representation err ~2^-22 rel)
__global__ __launch_bounds__(256) void convert_kernel(const float* __restrict__ src,
                                                      _Float16* __restrict__ hi,
                                                      _Float16* __restrict__ lo,
                                                      int ngr) {
    int g = blockIdx.x * 256 + threadIdx.x;   // one 8-float granule per thread
    if (g >= ngr) return;
    const float4* s4 = (const float4*)src + (size_t)g * 2;
    float4 x = s4[0], y = s4[1];
    float v[8] = {x.x, x.y, x.z, x.w, y.x, y.y, y.z, y.w};
    half8 h, l;
    #pragma unroll
    for (int i = 0; i < 8; ++i) {
        _Float16 hv = (_Float16)v[i];
        h[i] = hv;
        l[i] = (_Float16)((v[i] - (float)hv) * 2048.0f);
    }
    *(half8*)(hi + (size_t)g * 8) = h;
    *(half8*)(lo + (size_t)g * 8) = l;
}

// ---------------- cnorm: ||c_k||^2 in fp64, stored fp32 ----------------
__global__ __launch_bounds__(256) void cnorm_kernel(const float* __restrict__ cb,
                                                    float* __restrict__ cnorm) {
    int wave = threadIdx.x >> 6;
    int lane = threadIdx.x & 63;
    int k = blockIdx.x * 4 + wave;
    const float* row = cb + (size_t)k * DIM;
    float4 v = *(const float4*)(row + lane * 4);
    double s = (double)v.x * v.x + (double)v.y * v.y + (double)v.z * v.z + (double)v.w * v.w;
    #pragma unroll
    for (int off = 32; off; off >>= 1) s += __shfl_down(s, off, 64);
    if (lane == 0) cnorm[k] = (float)s;
}

// ---------------- distance screen: MFMA 16x16x32_f16 (ladder-verified layout) ----------------
// block tile: 128 codes (A/M) x 128 z (B/N), BK=32; 4 waves 2x2, wave = 64x64 as 4x4 16-tiles.
// Emits per-(z-row, code-block) best packed key (dist<<32 | code) to cand — no atomics.
__global__ __launch_bounds__(256, 2) void dist_kernel(const _Float16* __restrict__ zh,
                                                      const _Float16* __restrict__ zl,
                                                      const _Float16* __restrict__ ch,
                                                      const _Float16* __restrict__ cl,
                                                      const float* __restrict__ cnorm,
                                                      unsigned long long* __restrict__ cand) {
    // group-major LDS: [kgroup][row][8 halfs] — fragment reads are 16 consecutive
    // 16B slots per 16-lane group (2-way bank aliasing = free)
    __shared__ __align__(16) _Float16 Ah[4][128][8];
    __shared__ __align__(16) _Float16 Al[4][128][8];
    __shared__ __align__(16) _Float16 Bh[4][128][8];
    __shared__ __align__(16) _Float16 Bl[4][128][8];
    __shared__ unsigned long long red[2][128];

    const int tid = threadIdx.x;
    const int w = tid >> 6, lane = tid & 63;
    const int wr = w >> 1;   // code half (M)
    const int wc = w & 1;    // z half (N)
    const int zbase = blockIdx.x * 128;
    const int cbase = blockIdx.y * 128;
    const int c16 = lane & 15;   // fragment row/col within 16-tile
    const int g4 = lane >> 4;    // k-group (8 halfs)

    f32x4 hh[4][4], xx[4][4];
    #pragma unroll
    for (int i = 0; i < 4; ++i)
        #pragma unroll
        for (int j = 0; j < 4; ++j) { hh[i][j] = 0.0f; xx[i][j] = 0.0f; }

    for (int kc = 0; kc < 8; ++kc) {
        // stage 4 plane-tiles of 128 rows x 32 halfs; 512 granules (16B) per plane
        #pragma unroll
        for (int l = 0; l < 2; ++l) {
            int g = tid + l * 256;
            int r = g >> 2, gk = g & 3;
            size_t goC = (size_t)(cbase + r) * DIM + kc * 32 + gk * 8;
            size_t goZ = (size_t)(zbase + r) * DIM + kc * 32 + gk * 8;
            *(half8*)&Ah[gk][r][0] = *(const half8*)(ch + goC);
            *(half8*)&Al[gk][r][0] = *(const half8*)(cl + goC);
            *(half8*)&Bh[gk][r][0] = *(const half8*)(zh + goZ);
            *(half8*)&Bl[gk][r][0] = *(const half8*)(zl + goZ);
        }
        __syncthreads();

        half8 ah[4], al[4], bh[4], bl[4];
        #pragma unroll
        for (int i = 0; i < 4; ++i) {
            int r = wr * 64 + i * 16 + c16;
            ah[i] = *(const half8*)&Ah[g4][r][0];
            al[i] = *(const half8*)&Al[g4][r][0];
        }
        #pragma unroll
        for (int j = 0; j < 4; ++j) {
            int r = wc * 64 + j * 16 + c16;
            bh[j] = *(const half8*)&Bh[g4][r][0];
            bl[j] = *(const half8*)&Bl[g4][r][0];
        }
        #pragma unroll
        for (int i = 0; i < 4; ++i)
            #pragma unroll
            for (int j = 0; j < 4; ++j) {
                hh[i][j] = __builtin_amdgcn_mfma_f32_16x16x32_f16(ah[i], bh[j], hh[i][j], 0, 0, 0);
                xx[i][j] = __builtin_amdgcn_mfma_f32_16x16x32_f16(ah[i], bl[j], xx[i][j], 0, 0, 0);
                xx[i][j] = __builtin_amdgcn_mfma_f32_16x16x32_f16(al[i], bh[j], xx[i][j], 0, 0, 0);
            }
        __syncthreads();
    }

    // epilogue: C/D 16x16 layout (verified): col = lane&15 (z), row = (lane>>4)*4 + reg (code)
    #pragma unroll
    for (int j = 0; j < 4; ++j) {
        unsigned long long best = ~0ull;
        #pragma unroll
        for (int i = 0; i < 4; ++i) {
            #pragma unroll
            for (int reg = 0; reg < 4; ++reg) {
                int code = cbase + wr * 64 + i * 16 + g4 * 4 + reg;
                float dot = hh[i][j][reg] + xx[i][j][reg] * (1.0f / 2048.0f);
                float d = cnorm[code] - 2.0f * dot;
                unsigned u = __float_as_uint(d);
                u ^= ((int)u < 0) ? 0xFFFFFFFFu : 0x80000000u;  // order-preserving
                unsigned long long key = ((unsigned long long)u << 32) | (unsigned)code;
                if (key < best) best = key;
            }
        }
        // combine the 4 lane-groups covering the same z-col
        unsigned long long o = __shfl_xor(best, 16);
        if (o < best) best = o;
        o = __shfl_xor(best, 32);
        if (o < best) best = o;
        if (lane < 16) red[wr][wc * 64 + j * 16 + lane] = best;
    }
    __syncthreads();
    if (tid < 128) {
        unsigned long long a = red[0][tid], b = red[1][tid];
        cand[(size_t)(zbase + tid) * 64 + blockIdx.y] = (a < b) ? a : b;
    }
}

__device__ inline float decode_key(unsigned e) {
    unsigned orig = (e & 0x80000000u) ? (e ^ 0x80000000u) : ~e;
    return __uint_as_float(orig);
}

// ---------------- rescore: per row, fp64-rescore candidates within margin ----------------
__global__ __launch_bounds__(256) void rescore_kernel(const float* __restrict__ z,
                                                      const float* __restrict__ cb,
                                                      const unsigned long long* __restrict__ cand,
                                                      unsigned long long* __restrict__ keys) {
    int w = threadIdx.x >> 6, lane = threadIdx.x & 63;
    int row = blockIdx.x * 4 + w;
    unsigned long long k64 = cand[(size_t)row * 64 + lane];
    unsigned long long m = k64;
    #pragma unroll
    for (int off = 32; off; off >>= 1) {
        unsigned long long o = __shfl_xor(m, off);
        if (o < m) m = o;
    }
    float fmin = decode_key((unsigned)(m >> 32));
    float f = decode_key((unsigned)(k64 >> 32));
    unsigned long long mask = __ballot(f <= fmin + 0.5f);

    float4 z4 = *(const float4*)(z + (size_t)row * DIM + lane * 4);
    double bd = 1e300;
    int bc = 0x7fffffff;
    while (mask) {
        int src = __ffsll((unsigned long long)mask) - 1;
        mask &= mask - 1;
        int code = (int)(unsigned)__shfl(k64, src);
        float4 c4 = *(const float4*)(cb + (size_t)code * DIM + lane * 4);
        double d0 = (double)z4.x - c4.x, d1 = (double)z4.y - c4.y;
        double d2 = (double)z4.z - c4.z, d3 = (double)z4.w - c4.w;
        double s = d0 * d0 + d1 * d1 + d2 * d2 + d3 * d3;
        #pragma unroll
        for (int off = 32; off; off >>= 1) s += __shfl_xor(s, off);
        if (s < bd || (s == bd && code < bc)) { bd = s; bc = code; }
    }
    if (lane == 0) keys[row] = (unsigned long long)(unsigned)bc;
}

// ---------------- assign: z_q, idx, loss partial, count/mean scatter ----------------
__global__ __launch_bounds__(256) void assign_kernel(const float* __restrict__ z,
                                                     const float* __restrict__ cb,
                                                     const unsigned long long* __restrict__ keys,
                                                     float* __restrict__ zq_out,
                                                     float* __restrict__ idx_out,
                                                     float* __restrict__ counts,
                                                     float* __restrict__ meanAcc,
                                                     float* __restrict__ lossSum) {
    int wave = threadIdx.x >> 6, lane = threadIdx.x & 63;
    int row = blockIdx.x * 4 + wave;
    int idx = (int)(unsigned)(keys[row] & 0xFFFFFFFFull);
    float4 zv = *(const float4*)(z + (size_t)row * DIM + lane * 4);
    float4 cv = *(const float4*)(cb + (size_t)idx * DIM + lane * 4);
    *(float4*)(zq_out + (size_t)row * DIM + lane * 4) = cv;
    float d0 = zv.x - cv.x, d1 = zv.y - cv.y, d2 = zv.z - cv.z, d3 = zv.w - cv.w;
    float ls = d0 * d0 + d1 * d1 + d2 * d2 + d3 * d3;
    #pragma unroll
    for (int off = 32; off; off >>= 1) ls += __shfl_down(ls, off, 64);
    float* m = meanAcc + (size_t)idx * DIM + lane * 4;
    atomicAdd(m + 0, zv.x);
    atomicAdd(m + 1, zv.y);
    atomicAdd(m + 2, zv.z);
    atomicAdd(m + 3, zv.w);
    if (lane == 0) {
        idx_out[row] = (float)idx;
        atomicAdd(counts + idx, 1.0f);
        atomicAdd(lossSum, ls);
    }
}

// ---------------- count finalize + n + loss scalar ----------------
__global__ __launch_bounds__(1024) void count_final_kernel(const float* __restrict__ ema_count,
                                                           const float* __restrict__ counts,
                                                           float* __restrict__ newCount_out,
                                                           float* __restrict__ nOut,
                                                           const float* __restrict__ lossSum,
                                                           float* __restrict__ loss_out) {
    __shared__ float sred[1024];
    const float OMD = (float)(1.0 - 0.99);
    int tid = threadIdx.x;
    float s = 0.f;
    #pragma unroll
    for (int k = tid; k < K_CODES; k += 1024) {
        float nc = 0.99f * ema_count[k] + OMD * counts[k];
        newCount_out[k] = nc;
        s += nc;
    }
    sred[tid] = s;
    __syncthreads();
    for (int off = 512; off; off >>= 1) {
        if (tid < off) sred[tid] += sred[tid + off];
        __syncthreads();
    }
    if (tid == 0) {
        nOut[0] = sred[0];
        loss_out[0] = 1.25f * lossSum[0] / 4194304.0f;
    }
}

// ---------------- mean finalize + new codebook ----------------
__global__ __launch_bounds__(256) void final_kernel(const float* __restrict__ ema_mean,
                                                    const float* __restrict__ meanAcc,
                                                    const float* __restrict__ newCount,
                                                    const float* __restrict__ nPtr,
                                                    float* __restrict__ newMean_out,
                                                    float* __restrict__ newCb_out) {
    const float OMD = (float)(1.0 - 0.99);
    int g = blockIdx.x * 256 + threadIdx.x;
    int k = g >> 6;
    int c4 = (g & 63) * 4;
    float n = nPtr[0];
    float nc = newCount[k];
    float cs = (nc + 1e-5f) / (n + (float)(K_CODES * 1e-5)) * n;
    size_t base = (size_t)k * DIM + c4;
    float4 em = *(const float4*)(ema_mean + base);
    float4 mm = *(const float4*)(meanAcc + base);
    float4 nm;
    nm.x = 0.99f * em.x + OMD * mm.x;
    nm.y = 0.99f * em.y + OMD * mm.y;
    nm.z = 0.99f * em.z + OMD * mm.z;
    nm.w = 0.99f * em.w + OMD * mm.w;
    *(float4*)(newMean_out + base) = nm;
    float4 cbv;
    cbv.x = nm.x / cs;
    cbv.y = nm.y / cs;
    cbv.z = nm.z / cs;
    cbv.w = nm.w / cs;
    *(float4*)(newCb_out + base) = cbv;
}

extern "C" void kernel_launch(void* const* d_in, const int* in_sizes, int n_in,
                              void* d_out, int out_size, void* d_ws, size_t ws_size,
                              hipStream_t stream) {
    const float* z         = (const float*)d_in[0];
    const float* cb        = (const float*)d_in[1];
    const float* ema_count = (const float*)d_in[2];
    const float* ema_mean  = (const float*)d_in[3];
    float* out = (float*)d_out;
    char* ws = (char*)d_ws;

    unsigned long long* keys = (unsigned long long*)(ws + WS_KEYS);
    float* counts  = (float*)(ws + WS_COUNTS);
    float* cnorm   = (float*)(ws + WS_CNORM);
    float* lossSum = (float*)(ws + WS_LOSS);
    float* nPtr    = (float*)(ws + WS_N);
    float* meanAcc = (float*)(ws + WS_MEAN);

    _Float16* zh = (_Float16*)(out + POFF_ZH);
    _Float16* zl = (_Float16*)(out + POFF_ZL);
    _Float16* ch = (_Float16*)(out + POFF_CH);
    _Float16* cl = (_Float16*)(out + POFF_CL);
    unsigned long long* cand = (unsigned long long*)(out + POFF_CAND);

    hipMemsetAsync(ws + WS_COUNTS, 0, WS_END - WS_COUNTS, stream);

    convert_kernel<<<(N_ROWS * DIM / 8) / 256, 256, 0, stream>>>(z, zh, zl, N_ROWS * DIM / 8);
    convert_kernel<<<(K_CODES * DIM / 8) / 256, 256, 0, stream>>>(cb, ch, cl, K_CODES * DIM / 8);
    cnorm_kernel<<<K_CODES / 4, 256, 0, stream>>>(cb, cnorm);
    dist_kernel<<<dim3(N_ROWS / 128, K_CODES / 128), 256, 0, stream>>>(zh, zl, ch, cl, cnorm, cand);
    rescore_kernel<<<N_ROWS / 4, 256, 0, stream>>>(z, cb, cand, keys);
    assign_kernel<<<N_ROWS / 4, 256, 0, stream>>>(z, cb, keys, out + OFF_ZQ, out + OFF_IDX,
                                                  counts, meanAcc, lossSum);
    count_final_kernel<<<1, 1024, 0, stream>>>(ema_count, counts, out + OFF_CNT, nPtr,
                                               lossSum, out + OFF_LOSS);
    final_kernel<<<(K_CODES * DIM / 4) / 256, 256, 0, stream>>>(ema_mean, meanAcc,
                                                                out + OFF_CNT, nPtr,
                                                                out + OFF_MEAN, out + OFF_CB);
}

// Round 5
// 391.034 us; speedup vs baseline: 2.8120x; 1.3413x over previous
//
#include <hip/hip_runtime.h>

// ---- problem constants ----
#define N_ROWS 16384   // 8*16*128
#define DIM    256
#define K_CODES 8192

// output layout (flat float32, return order)
#define OFF_ZQ   0
#define OFF_LOSS 4194304
#define OFF_IDX  4194305
#define OFF_CB   4210689
#define OFF_CNT  6307841
#define OFF_MEAN 6316033

// d_out scratch (all consumed before the real outputs overwrite, stream-ordered):
//   zhp  [0 .. 2097152) floats        — permuted fp16 z, dead after dist
//   chp  [2097152 .. 3145728) floats  — permuted fp16 codebook, dead after dist
//   cand [4210692 .. 6307844) floats  — u64[16384*64] top-2 keys; inside CB region
//        (3-float spill into CNT, rewritten by count_final afterwards);
//        disjoint from zq/loss/idx which rescore_assign writes while reading cand.
#define POFF_ZHP  0
#define POFF_CHP  2097152
#define POFF_CAND 4210692

// workspace layout (bytes)
#define WS_COUNTS 0        // f32[8192]
#define WS_CNORM  32768    // f32[8192]
#define WS_LOSS   65536    // f32
#define WS_N      65540    // f32
#define WS_MEAN   65552    // f32[8192*256] = 8388608 -> ends 8454160
#define WS_END    8454160

typedef _Float16 half8 __attribute__((ext_vector_type(8)));
typedef _Float16 half4 __attribute__((ext_vector_type(4)));
typedef float f32x4 __attribute__((ext_vector_type(4)));

// ---------------- convert z -> permuted fp16 hi plane ----------------
// zhp granule order: [zblk(128)][kc(8)][gk(4)][r(128)][8 halfs]
__global__ __launch_bounds__(256) void convert_z_kernel(const float* __restrict__ z,
                                                        _Float16* __restrict__ zhp) {
    int G = blockIdx.x * 256 + threadIdx.x;   // row-major granule id
    int row = G >> 5, c8 = G & 31;
    const float4* s = (const float4*)(z + (size_t)row * DIM + c8 * 8);
    float4 x = s[0], y = s[1];
    float v[8] = {x.x, x.y, x.z, x.w, y.x, y.y, y.z, y.w};
    half8 h;
    #pragma unroll
    for (int i = 0; i < 8; ++i) h[i] = (_Float16)v[i];
    int zblk = row >> 7, r = row & 127, kc = c8 >> 2, gk = c8 & 3;
    size_t o = ((size_t)((zblk * 8 + kc) * 4 + gk) * 128 + r) * 8;
    *(half8*)(zhp + o) = h;
}

// ---------------- convert cb -> permuted fp16 hi plane + fp64 cnorm ----------------
// chp granule order: [cblk(32)][kc(8)][gk(4)][r(256)][8 halfs]; one wave per cb row
__global__ __launch_bounds__(256) void convert_cb_kernel(const float* __restrict__ cb,
                                                         _Float16* __restrict__ chp,
                                                         float* __restrict__ cnorm) {
    int w = threadIdx.x >> 6, lane = threadIdx.x & 63;
    int row = blockIdx.x * 4 + w;
    float4 v = *(const float4*)(cb + (size_t)row * DIM + lane * 4);
    half4 h;
    h[0] = (_Float16)v.x; h[1] = (_Float16)v.y; h[2] = (_Float16)v.z; h[3] = (_Float16)v.w;
    int c8 = lane >> 1, pos = (lane & 1) * 4;
    int cblk = row >> 8, r = row & 255, kc = c8 >> 2, gk = c8 & 3;
    size_t o = ((size_t)((cblk * 8 + kc) * 4 + gk) * 256 + r) * 8 + pos;
    *(half4*)(chp + o) = h;
    double s = (double)v.x * v.x + (double)v.y * v.y + (double)v.z * v.z + (double)v.w * v.w;
    #pragma unroll
    for (int off = 32; off; off >>= 1) s += __shfl_down(s, off, 64);
    if (lane == 0) cnorm[row] = (float)s;
}

// ---------------- distance screen: hh-only fp16 MFMA, top-2 per block ----------------
// tile: 256 codes x 128 z, 4 waves, wave = 64 codes x 128 z (4i x 8j of 16x16x32).
__global__ __launch_bounds__(256, 2) void dist_kernel(const _Float16* __restrict__ zhp,
                                                      const _Float16* __restrict__ chp,
                                                      const float* __restrict__ cnorm,
                                                      unsigned long long* __restrict__ cand) {
    __shared__ __align__(16) _Float16 Ah[1024 * 8];         // 16KB [gk][256][8]
    __shared__ __align__(16) _Float16 Bh[512 * 8];          // 8KB  [gk][128][8]
    __shared__ unsigned long long red[4][128][2];           // 8KB

    const int tid = threadIdx.x;
    const int w = tid >> 6, lane = tid & 63;
    const int c16 = lane & 15, g4 = lane >> 4;
    const int zbX = blockIdx.x, cbY = blockIdx.y;

    f32x4 acc[4][8];
    #pragma unroll
    for (int i = 0; i < 4; ++i)
        #pragma unroll
        for (int j = 0; j < 8; ++j) acc[i][j] = 0.0f;

    for (int kc = 0; kc < 8; ++kc) {
        const _Float16* As = chp + (size_t)(cbY * 8 + kc) * 8192;
        const _Float16* Bs = zhp + (size_t)(zbX * 8 + kc) * 4096;
        // issue global loads early (overlap with previous compute)
        half8 st[6];
        #pragma unroll
        for (int t = 0; t < 4; ++t) st[t] = *(const half8*)(As + ((size_t)((t * 4 + w) * 64 + lane)) * 8);
        #pragma unroll
        for (int t = 0; t < 2; ++t) st[4 + t] = *(const half8*)(Bs + ((size_t)((t * 4 + w) * 64 + lane)) * 8);
        __syncthreads();   // previous iter's LDS reads done
        #pragma unroll
        for (int t = 0; t < 4; ++t) *(half8*)(Ah + ((size_t)((t * 4 + w) * 64 + lane)) * 8) = st[t];
        #pragma unroll
        for (int t = 0; t < 2; ++t) *(half8*)(Bh + ((size_t)((t * 4 + w) * 64 + lane)) * 8) = st[4 + t];
        __syncthreads();

        half8 bh[8];
        #pragma unroll
        for (int j = 0; j < 8; ++j)
            bh[j] = *(const half8*)(Bh + ((size_t)g4 * 128 + j * 16 + c16) * 8);
        #pragma unroll
        for (int i = 0; i < 4; ++i) {
            half8 ah = *(const half8*)(Ah + ((size_t)g4 * 256 + w * 64 + i * 16 + c16) * 8);
            #pragma unroll
            for (int j = 0; j < 8; ++j)
                acc[i][j] = __builtin_amdgcn_mfma_f32_16x16x32_f16(ah, bh[j], acc[i][j], 0, 0, 0);
        }
    }

    // epilogue: top-2 per (z-col, 256-code block); C/D: col=lane&15 (z), row=(lane>>4)*4+reg (code)
    #pragma unroll
    for (int j = 0; j < 8; ++j) {
        unsigned long long b1 = ~0ull, b2 = ~0ull;
        #pragma unroll
        for (int i = 0; i < 4; ++i) {
            #pragma unroll
            for (int reg = 0; reg < 4; ++reg) {
                int code = cbY * 256 + w * 64 + i * 16 + g4 * 4 + reg;
                float d = cnorm[code] - 2.0f * acc[i][j][reg];
                unsigned u = __float_as_uint(d);
                u ^= ((int)u < 0) ? 0xFFFFFFFFu : 0x80000000u;
                unsigned long long key = ((unsigned long long)u << 32) | (unsigned)code;
                if (key < b1) { b2 = b1; b1 = key; }
                else if (key < b2) { b2 = key; }
            }
        }
        #pragma unroll
        for (int off = 16; off <= 32; off <<= 1) {
            unsigned long long o1 = __shfl_xor(b1, off), o2 = __shfl_xor(b2, off);
            unsigned long long m1 = (b1 < o1) ? b1 : o1;
            unsigned long long hi = (b1 < o1) ? o1 : b1;
            unsigned long long m2 = (b2 < o2) ? b2 : o2;
            b1 = m1; b2 = (m2 < hi) ? m2 : hi;
        }
        if (lane < 16) { red[w][j * 16 + lane][0] = b1; red[w][j * 16 + lane][1] = b2; }
    }
    __syncthreads();
    if (tid < 128) {
        unsigned long long b1 = ~0ull, b2 = ~0ull;
        #pragma unroll
        for (int t = 0; t < 4; ++t) {
            unsigned long long o1 = red[t][tid][0], o2 = red[t][tid][1];
            unsigned long long m1 = (b1 < o1) ? b1 : o1;
            unsigned long long hi = (b1 < o1) ? o1 : b1;
            unsigned long long m2 = (b2 < o2) ? b2 : o2;
            b1 = m1; b2 = (m2 < hi) ? m2 : hi;
        }
        size_t base = (size_t)(zbX * 128 + tid) * 64 + cbY * 2;
        cand[base] = b1;
        cand[base + 1] = b2;
    }
}

__device__ inline float decode_key(unsigned e) {
    unsigned orig = (e & 0x80000000u) ? (e ^ 0x80000000u) : ~e;
    return __uint_as_float(orig);
}

// ---------------- rescore (fp64 within margin) + assign, fused ----------------
__global__ __launch_bounds__(256) void rescore_assign_kernel(const float* __restrict__ z,
                                                             const float* __restrict__ cb,
                                                             const unsigned long long* __restrict__ cand,
                                                             float* __restrict__ zq_out,
                                                             float* __restrict__ idx_out,
                                                             float* __restrict__ counts,
                                                             float* __restrict__ meanAcc,
                                                             float* __restrict__ lossSum) {
    int w = threadIdx.x >> 6, lane = threadIdx.x & 63;
    int row = blockIdx.x * 4 + w;
    unsigned long long k64 = cand[(size_t)row * 64 + lane];
    unsigned long long m = k64;
    #pragma unroll
    for (int off = 32; off; off >>= 1) {
        unsigned long long o = __shfl_xor(m, off);
        if (o < m) m = o;
    }
    float fmin = decode_key((unsigned)(m >> 32));
    float f = decode_key((unsigned)(k64 >> 32));
    unsigned long long mask = __ballot(f <= fmin + 1.0f);

    float4 zv = *(const float4*)(z + (size_t)row * DIM + lane * 4);
    double bd = 1e300;
    int bc = 0x7fffffff;
    while (mask) {
        int src = __ffsll((unsigned long long)mask) - 1;
        mask &= mask - 1;
        int code = (int)(unsigned)__shfl(k64, src);
        float4 c4 = *(const float4*)(cb + (size_t)code * DIM + lane * 4);
        double d0 = (double)zv.x - c4.x, d1 = (double)zv.y - c4.y;
        double d2 = (double)zv.z - c4.z, d3 = (double)zv.w - c4.w;
        double s = d0 * d0 + d1 * d1 + d2 * d2 + d3 * d3;
        #pragma unroll
        for (int off = 32; off; off >>= 1) s += __shfl_xor(s, off);
        if (s < bd || (s == bd && code < bc)) { bd = s; bc = code; }
    }

    float4 cv = *(const float4*)(cb + (size_t)bc * DIM + lane * 4);
    *(float4*)(zq_out + (size_t)row * DIM + lane * 4) = cv;
    float d0 = zv.x - cv.x, d1 = zv.y - cv.y, d2 = zv.z - cv.z, d3 = zv.w - cv.w;
    float ls = d0 * d0 + d1 * d1 + d2 * d2 + d3 * d3;
    #pragma unroll
    for (int off = 32; off; off >>= 1) ls += __shfl_down(ls, off, 64);
    float* mp = meanAcc + (size_t)bc * DIM + lane * 4;
    atomicAdd(mp + 0, zv.x);
    atomicAdd(mp + 1, zv.y);
    atomicAdd(mp + 2, zv.z);
    atomicAdd(mp + 3, zv.w);
    if (lane == 0) {
        idx_out[row] = (float)bc;
        atomicAdd(counts + bc, 1.0f);
        atomicAdd(lossSum, ls);
    }
}

// ---------------- count finalize + n + loss scalar ----------------
__global__ __launch_bounds__(1024) void count_final_kernel(const float* __restrict__ ema_count,
                                                           const float* __restrict__ counts,
                                                           float* __restrict__ newCount_out,
                                                           float* __restrict__ nOut,
                                                           const float* __restrict__ lossSum,
                                                           float* __restrict__ loss_out) {
    __shared__ float sred[1024];
    const float OMD = (float)(1.0 - 0.99);
    int tid = threadIdx.x;
    float s = 0.f;
    #pragma unroll
    for (int k = tid; k < K_CODES; k += 1024) {
        float nc = 0.99f * ema_count[k] + OMD * counts[k];
        newCount_out[k] = nc;
        s += nc;
    }
    sred[tid] = s;
    __syncthreads();
    for (int off = 512; off; off >>= 1) {
        if (tid < off) sred[tid] += sred[tid + off];
        __syncthreads();
    }
    if (tid == 0) {
        nOut[0] = sred[0];
        loss_out[0] = 1.25f * lossSum[0] / 4194304.0f;
    }
}

// ---------------- mean finalize + new codebook ----------------
__global__ __launch_bounds__(256) void final_kernel(const float* __restrict__ ema_mean,
                                                    const float* __restrict__ meanAcc,
                                                    const float* __restrict__ newCount,
                                                    const float* __restrict__ nPtr,
                                                    float* __restrict__ newMean_out,
                                                    float* __restrict__ newCb_out) {
    const float OMD = (float)(1.0 - 0.99);
    int g = blockIdx.x * 256 + threadIdx.x;
    int k = g >> 6;
    int c4 = (g & 63) * 4;
    float n = nPtr[0];
    float nc = newCount[k];
    float cs = (nc + 1e-5f) / (n + (float)(K_CODES * 1e-5)) * n;
    size_t base = (size_t)k * DIM + c4;
    float4 em = *(const float4*)(ema_mean + base);
    float4 mm = *(const float4*)(meanAcc + base);
    float4 nm;
    nm.x = 0.99f * em.x + OMD * mm.x;
    nm.y = 0.99f * em.y + OMD * mm.y;
    nm.z = 0.99f * em.z + OMD * mm.z;
    nm.w = 0.99f * em.w + OMD * mm.w;
    *(float4*)(newMean_out + base) = nm;
    float4 cbv;
    cbv.x = nm.x / cs;
    cbv.y = nm.y / cs;
    cbv.z = nm.z / cs;
    cbv.w = nm.w / cs;
    *(float4*)(newCb_out + base) = cbv;
}

extern "C" void kernel_launch(void* const* d_in, const int* in_sizes, int n_in,
                              void* d_out, int out_size, void* d_ws, size_t ws_size,
                              hipStream_t stream) {
    const float* z         = (const float*)d_in[0];
    const float* cb        = (const float*)d_in[1];
    const float* ema_count = (const float*)d_in[2];
    const float* ema_mean  = (const float*)d_in[3];
    float* out = (float*)d_out;
    char* ws = (char*)d_ws;

    float* counts  = (float*)(ws + WS_COUNTS);
    float* cnorm   = (float*)(ws + WS_CNORM);
    float* lossSum = (float*)(ws + WS_LOSS);
    float* nPtr    = (float*)(ws + WS_N);
    float* meanAcc = (float*)(ws + WS_MEAN);

    _Float16* zhp = (_Float16*)(out + POFF_ZHP);
    _Float16* chp = (_Float16*)(out + POFF_CHP);
    unsigned long long* cand = (unsigned long long*)(out + POFF_CAND);

    hipMemsetAsync(ws, 0, WS_END, stream);

    convert_z_kernel<<<(N_ROWS * DIM / 8) / 256, 256, 0, stream>>>(z, zhp);
    convert_cb_kernel<<<K_CODES / 4, 256, 0, stream>>>(cb, chp, cnorm);
    dist_kernel<<<dim3(N_ROWS / 128, K_CODES / 256), 256, 0, stream>>>(zhp, chp, cnorm, cand);
    rescore_assign_kernel<<<N_ROWS / 4, 256, 0, stream>>>(z, cb, cand, out + OFF_ZQ,
                                                          out + OFF_IDX, counts, meanAcc, lossSum);
    count_final_kernel<<<1, 1024, 0, stream>>>(ema_count, counts, out + OFF_CNT, nPtr,
                                               lossSum, out + OFF_LOSS);
    final_kernel<<<(K_CODES * DIM / 4) / 256, 256, 0, stream>>>(ema_mean, meanAcc,
                                                                out + OFF_CNT, nPtr,
                                                                out + OFF_MEAN, out + OFF_CB);
}

// Round 6
// 235.376 us; speedup vs baseline: 4.6716x; 1.6613x over previous
//
#include <hip/hip_runtime.h>

// ---- problem constants ----
#define N_ROWS 16384   // 8*16*128
#define DIM    256
#define K_CODES 8192

// output layout (flat float32, return order)
#define OFF_ZQ   0
#define OFF_LOSS 4194304
#define OFF_IDX  4194305
#define OFF_CB   4210689
#define OFF_CNT  6307841
#define OFF_MEAN 6316033

// d_out scratch (all consumed before the real outputs overwrite, stream-ordered):
//   zhp  [0 .. 2097152) floats        — permuted fp16 z, dead after dist
//   chp  [2097152 .. 3145728) floats  — permuted fp16 codebook, dead after dist
//   cand [4210692 .. 6307844) floats  — u64[16384*64] top-2 keys; inside CB region
#define POFF_ZHP  0
#define POFF_CHP  2097152
#define POFF_CAND 4210692

// workspace layout (bytes)
#define WS_COUNTS 0        // f32[8192]
#define WS_CNORM  32768    // f32[8192]
#define WS_LOSSP  65536    // f32[4096] per-block loss partials -> ends 81920
#define WS_N      81920    // f32
#define WS_MEAN   98304    // f32[8192*256] = 8388608 -> ends 8486912
#define WS_END    8486912

typedef _Float16 half8 __attribute__((ext_vector_type(8)));
typedef _Float16 half4 __attribute__((ext_vector_type(4)));
typedef float f32x4 __attribute__((ext_vector_type(4)));

// ---------------- convert z -> permuted fp16 hi plane ----------------
// zhp granule order: [zblk(128)][kc(8)][gk(4)][r(128)][8 halfs]
__global__ __launch_bounds__(256) void convert_z_kernel(const float* __restrict__ z,
                                                        _Float16* __restrict__ zhp) {
    int G = blockIdx.x * 256 + threadIdx.x;   // row-major granule id
    int row = G >> 5, c8 = G & 31;
    const float4* s = (const float4*)(z + (size_t)row * DIM + c8 * 8);
    float4 x = s[0], y = s[1];
    float v[8] = {x.x, x.y, x.z, x.w, y.x, y.y, y.z, y.w};
    half8 h;
    #pragma unroll
    for (int i = 0; i < 8; ++i) h[i] = (_Float16)v[i];
    int zblk = row >> 7, r = row & 127, kc = c8 >> 2, gk = c8 & 3;
    size_t o = ((size_t)((zblk * 8 + kc) * 4 + gk) * 128 + r) * 8;
    *(half8*)(zhp + o) = h;
}

// ---------------- convert cb -> permuted fp16 hi plane + fp64 cnorm ----------------
// chp granule order: [cblk(32)][kc(8)][gk(4)][r(256)][8 halfs]; one wave per cb row
__global__ __launch_bounds__(256) void convert_cb_kernel(const float* __restrict__ cb,
                                                         _Float16* __restrict__ chp,
                                                         float* __restrict__ cnorm) {
    int w = threadIdx.x >> 6, lane = threadIdx.x & 63;
    int row = blockIdx.x * 4 + w;
    float4 v = *(const float4*)(cb + (size_t)row * DIM + lane * 4);
    half4 h;
    h[0] = (_Float16)v.x; h[1] = (_Float16)v.y; h[2] = (_Float16)v.z; h[3] = (_Float16)v.w;
    int c8 = lane >> 1, pos = (lane & 1) * 4;
    int cblk = row >> 8, r = row & 255, kc = c8 >> 2, gk = c8 & 3;
    size_t o = ((size_t)((cblk * 8 + kc) * 4 + gk) * 256 + r) * 8 + pos;
    *(half4*)(chp + o) = h;
    double s = (double)v.x * v.x + (double)v.y * v.y + (double)v.z * v.z + (double)v.w * v.w;
    #pragma unroll
    for (int off = 32; off; off >>= 1) s += __shfl_down(s, off, 64);
    if (lane == 0) cnorm[row] = (float)s;
}

// ---------------- distance screen: LDS-free direct-global MFMA, top-2 per block ----------------
// tile: 256 codes x 128 z, 4 waves, wave = 64 codes x 128 z (4i x 8j of 16x16x32).
// Fragments load straight from the pre-permuted global planes (256B contiguous per
// 16-lane group) — no staging, no barriers, no bank conflicts in the main loop.
__global__ __launch_bounds__(256, 2) void dist_kernel(const _Float16* __restrict__ zhp,
                                                      const _Float16* __restrict__ chp,
                                                      const float* __restrict__ cnorm,
                                                      unsigned long long* __restrict__ cand) {
    __shared__ unsigned long long red[4][128][2];           // 8KB, epilogue only

    const int tid = threadIdx.x;
    const int w = tid >> 6, lane = tid & 63;
    const int c16 = lane & 15, g4 = lane >> 4;
    const int zbX = blockIdx.x, cbY = blockIdx.y;

    f32x4 acc[4][8];
    #pragma unroll
    for (int i = 0; i < 4; ++i)
        #pragma unroll
        for (int j = 0; j < 8; ++j) acc[i][j] = 0.0f;

    #pragma unroll 2
    for (int kc = 0; kc < 8; ++kc) {
        const _Float16* Ap = chp + ((size_t)((cbY * 8 + kc) * 4 + g4)) * 2048 + (w * 64 + c16) * 8;
        const _Float16* Bp = zhp + ((size_t)((zbX * 8 + kc) * 4 + g4)) * 1024 + c16 * 8;
        half8 bh[8];
        #pragma unroll
        for (int j = 0; j < 8; ++j) bh[j] = *(const half8*)(Bp + j * 128);
        #pragma unroll
        for (int i = 0; i < 4; ++i) {
            half8 ah = *(const half8*)(Ap + i * 128);
            #pragma unroll
            for (int j = 0; j < 8; ++j)
                acc[i][j] = __builtin_amdgcn_mfma_f32_16x16x32_f16(ah, bh[j], acc[i][j], 0, 0, 0);
        }
    }

    // epilogue: top-2 per (z-col, 256-code block); C/D: col=lane&15 (z), row=(lane>>4)*4+reg (code)
    #pragma unroll
    for (int j = 0; j < 8; ++j) {
        unsigned long long b1 = ~0ull, b2 = ~0ull;
        #pragma unroll
        for (int i = 0; i < 4; ++i) {
            #pragma unroll
            for (int reg = 0; reg < 4; ++reg) {
                int code = cbY * 256 + w * 64 + i * 16 + g4 * 4 + reg;
                float d = cnorm[code] - 2.0f * acc[i][j][reg];
                unsigned u = __float_as_uint(d);
                u ^= ((int)u < 0) ? 0xFFFFFFFFu : 0x80000000u;
                unsigned long long key = ((unsigned long long)u << 32) | (unsigned)code;
                if (key < b1) { b2 = b1; b1 = key; }
                else if (key < b2) { b2 = key; }
            }
        }
        #pragma unroll
        for (int off = 16; off <= 32; off <<= 1) {
            unsigned long long o1 = __shfl_xor(b1, off), o2 = __shfl_xor(b2, off);
            unsigned long long m1 = (b1 < o1) ? b1 : o1;
            unsigned long long hi = (b1 < o1) ? o1 : b1;
            unsigned long long m2 = (b2 < o2) ? b2 : o2;
            b1 = m1; b2 = (m2 < hi) ? m2 : hi;
        }
        if (lane < 16) { red[w][j * 16 + lane][0] = b1; red[w][j * 16 + lane][1] = b2; }
    }
    __syncthreads();
    if (tid < 128) {
        unsigned long long b1 = ~0ull, b2 = ~0ull;
        #pragma unroll
        for (int t = 0; t < 4; ++t) {
            unsigned long long o1 = red[t][tid][0], o2 = red[t][tid][1];
            unsigned long long m1 = (b1 < o1) ? b1 : o1;
            unsigned long long hi = (b1 < o1) ? o1 : b1;
            unsigned long long m2 = (b2 < o2) ? b2 : o2;
            b1 = m1; b2 = (m2 < hi) ? m2 : hi;
        }
        size_t base = (size_t)(zbX * 128 + tid) * 64 + cbY * 2;
        cand[base] = b1;
        cand[base + 1] = b2;
    }
}

__device__ inline float decode_key(unsigned e) {
    unsigned orig = (e & 0x80000000u) ? (e ^ 0x80000000u) : ~e;
    return __uint_as_float(orig);
}

// ---------------- rescore (fp64 within margin) + assign, fused ----------------
__global__ __launch_bounds__(256) void rescore_assign_kernel(const float* __restrict__ z,
                                                             const float* __restrict__ cb,
                                                             const unsigned long long* __restrict__ cand,
                                                             float* __restrict__ zq_out,
                                                             float* __restrict__ idx_out,
                                                             float* __restrict__ counts,
                                                             float* __restrict__ meanAcc,
                                                             float* __restrict__ lossPart) {
    __shared__ float lred[4];
    int w = threadIdx.x >> 6, lane = threadIdx.x & 63;
    int row = blockIdx.x * 4 + w;
    unsigned long long k64 = cand[(size_t)row * 64 + lane];
    unsigned long long m = k64;
    #pragma unroll
    for (int off = 32; off; off >>= 1) {
        unsigned long long o = __shfl_xor(m, off);
        if (o < m) m = o;
    }
    float fmin = decode_key((unsigned)(m >> 32));
    float f = decode_key((unsigned)(k64 >> 32));
    unsigned long long mask = __ballot(f <= fmin + 1.0f);

    float4 zv = *(const float4*)(z + (size_t)row * DIM + lane * 4);
    double bd = 1e300;
    int bc = 0x7fffffff;
    while (mask) {
        int src = __ffsll((unsigned long long)mask) - 1;
        mask &= mask - 1;
        int code = (int)(unsigned)__shfl(k64, src);
        float4 c4 = *(const float4*)(cb + (size_t)code * DIM + lane * 4);
        double d0 = (double)zv.x - c4.x, d1 = (double)zv.y - c4.y;
        double d2 = (double)zv.z - c4.z, d3 = (double)zv.w - c4.w;
        double s = d0 * d0 + d1 * d1 + d2 * d2 + d3 * d3;
        #pragma unroll
        for (int off = 32; off; off >>= 1) s += __shfl_xor(s, off);
        if (s < bd || (s == bd && code < bc)) { bd = s; bc = code; }
    }

    float4 cv = *(const float4*)(cb + (size_t)bc * DIM + lane * 4);
    *(float4*)(zq_out + (size_t)row * DIM + lane * 4) = cv;
    float d0 = zv.x - cv.x, d1 = zv.y - cv.y, d2 = zv.z - cv.z, d3 = zv.w - cv.w;
    float ls = d0 * d0 + d1 * d1 + d2 * d2 + d3 * d3;
    #pragma unroll
    for (int off = 32; off; off >>= 1) ls += __shfl_down(ls, off, 64);
    float* mp = meanAcc + (size_t)bc * DIM + lane * 4;
    atomicAdd(mp + 0, zv.x);
    atomicAdd(mp + 1, zv.y);
    atomicAdd(mp + 2, zv.z);
    atomicAdd(mp + 3, zv.w);
    if (lane == 0) {
        idx_out[row] = (float)bc;
        atomicAdd(counts + bc, 1.0f);
        lred[w] = ls;
    }
    __syncthreads();
    if (threadIdx.x == 0)
        lossPart[blockIdx.x] = lred[0] + lred[1] + lred[2] + lred[3];
}

// ---------------- count finalize + n + loss scalar ----------------
__global__ __launch_bounds__(1024) void count_final_kernel(const float* __restrict__ ema_count,
                                                           const float* __restrict__ counts,
                                                           float* __restrict__ newCount_out,
                                                           float* __restrict__ nOut,
                                                           const float* __restrict__ lossPart,
                                                           float* __restrict__ loss_out) {
    __shared__ float sred[1024];
    const float OMD = (float)(1.0 - 0.99);
    int tid = threadIdx.x;
    float s = 0.f;
    #pragma unroll
    for (int k = tid; k < K_CODES; k += 1024) {
        float nc = 0.99f * ema_count[k] + OMD * counts[k];
        newCount_out[k] = nc;
        s += nc;
    }
    sred[tid] = s;
    __syncthreads();
    for (int off = 512; off; off >>= 1) {
        if (tid < off) sred[tid] += sred[tid + off];
        __syncthreads();
    }
    if (tid == 0) nOut[0] = sred[0];
    __syncthreads();
    float L = lossPart[tid] + lossPart[tid + 1024] + lossPart[tid + 2048] + lossPart[tid + 3072];
    sred[tid] = L;
    __syncthreads();
    for (int off = 512; off; off >>= 1) {
        if (tid < off) sred[tid] += sred[tid + off];
        __syncthreads();
    }
    if (tid == 0) loss_out[0] = 1.25f * sred[0] / 4194304.0f;
}

// ---------------- mean finalize + new codebook ----------------
__global__ __launch_bounds__(256) void final_kernel(const float* __restrict__ ema_mean,
                                                    const float* __restrict__ meanAcc,
                                                    const float* __restrict__ newCount,
                                                    const float* __restrict__ nPtr,
                                                    float* __restrict__ newMean_out,
                                                    float* __restrict__ newCb_out) {
    const float OMD = (float)(1.0 - 0.99);
    int g = blockIdx.x * 256 + threadIdx.x;
    int k = g >> 6;
    int c4 = (g & 63) * 4;
    float n = nPtr[0];
    float nc = newCount[k];
    float cs = (nc + 1e-5f) / (n + (float)(K_CODES * 1e-5)) * n;
    size_t base = (size_t)k * DIM + c4;
    float4 em = *(const float4*)(ema_mean + base);
    float4 mm = *(const float4*)(meanAcc + base);
    float4 nm;
    nm.x = 0.99f * em.x + OMD * mm.x;
    nm.y = 0.99f * em.y + OMD * mm.y;
    nm.z = 0.99f * em.z + OMD * mm.z;
    nm.w = 0.99f * em.w + OMD * mm.w;
    *(float4*)(newMean_out + base) = nm;
    float4 cbv;
    cbv.x = nm.x / cs;
    cbv.y = nm.y / cs;
    cbv.z = nm.z / cs;
    cbv.w = nm.w / cs;
    *(float4*)(newCb_out + base) = cbv;
}

extern "C" void kernel_launch(void* const* d_in, const int* in_sizes, int n_in,
                              void* d_out, int out_size, void* d_ws, size_t ws_size,
                              hipStream_t stream) {
    const float* z         = (const float*)d_in[0];
    const float* cb        = (const float*)d_in[1];
    const float* ema_count = (const float*)d_in[2];
    const float* ema_mean  = (const float*)d_in[3];
    float* out = (float*)d_out;
    char* ws = (char*)d_ws;

    float* counts   = (float*)(ws + WS_COUNTS);
    float* cnorm    = (float*)(ws + WS_CNORM);
    float* lossPart = (float*)(ws + WS_LOSSP);
    float* nPtr     = (float*)(ws + WS_N);
    float* meanAcc  = (float*)(ws + WS_MEAN);

    _Float16* zhp = (_Float16*)(out + POFF_ZHP);
    _Float16* chp = (_Float16*)(out + POFF_CHP);
    unsigned long long* cand = (unsigned long long*)(out + POFF_CAND);

    hipMemsetAsync(ws, 0, WS_END, stream);

    convert_z_kernel<<<(N_ROWS * DIM / 8) / 256, 256, 0, stream>>>(z, zhp);
    convert_cb_kernel<<<K_CODES / 4, 256, 0, stream>>>(cb, chp, cnorm);
    dist_kernel<<<dim3(N_ROWS / 128, K_CODES / 256), 256, 0, stream>>>(zhp, chp, cnorm, cand);
    rescore_assign_kernel<<<N_ROWS / 4, 256, 0, stream>>>(z, cb, cand, out + OFF_ZQ,
                                                          out + OFF_IDX, counts, meanAcc, lossPart);
    count_final_kernel<<<1, 1024, 0, stream>>>(ema_count, counts, out + OFF_CNT, nPtr,
                                               lossPart, out + OFF_LOSS);
    final_kernel<<<(K_CODES * DIM / 4) / 256, 256, 0, stream>>>(ema_mean, meanAcc,
                                                                out + OFF_CNT, nPtr,
                                                                out + OFF_MEAN, out + OFF_CB);
}

// Round 7
// 220.343 us; speedup vs baseline: 4.9903x; 1.0682x over previous
//
#include <hip/hip_runtime.h>

// ---- problem constants ----
#define N_ROWS 16384   // 8*16*128
#define DIM    256
#define K_CODES 8192

// output layout (flat float32, return order)
#define OFF_ZQ   0
#define OFF_LOSS 4194304
#define OFF_IDX  4194305
#define OFF_CB   4210689
#define OFF_CNT  6307841
#define OFF_MEAN 6316033

// d_out scratch (all consumed before the real outputs overwrite, stream-ordered):
//   zhp  [0 .. 2097152) floats        — permuted fp16 z, dead after dist
//   chp  [2097152 .. 3145728) floats  — permuted fp16 codebook, dead after dist
//   cand [4210692 .. 6307844) floats  — u64[16384*64] top-2 keys; inside CB region
#define POFF_ZHP  0
#define POFF_CHP  2097152
#define POFF_CAND 4210692

// workspace layout (bytes)
#define WS_COUNTS 0        // f32[8192]
#define WS_CNORM  32768    // f32[8192]
#define WS_LOSSP  65536    // f32[4096] -> ends 81920
#define WS_N      81920    // f32
#define WS_MEAN   98304    // f32[8192*256] = 8388608 -> ends 8486912

typedef _Float16 half8 __attribute__((ext_vector_type(8)));
typedef _Float16 half4 __attribute__((ext_vector_type(4)));
typedef float f32x4 __attribute__((ext_vector_type(4)));

// ---------------- prep: convert z + cb to permuted fp16 planes, cnorm, zero meanAcc ----------------
// zhp granule order: [zblk(128)][kc(8)][gk(4)][r(128)][8 halfs]
// chp granule order: [cblk(32)][kc(8)][gk(4)][r(256)][8 halfs]
__global__ __launch_bounds__(256) void prep_kernel(const float* __restrict__ z,
                                                   const float* __restrict__ cb,
                                                   _Float16* __restrict__ zhp,
                                                   _Float16* __restrict__ chp,
                                                   float* __restrict__ cnorm,
                                                   float* __restrict__ meanAcc) {
    int b = blockIdx.x;
    if (b < 2048) {                       // ---- z convert: one granule per thread
        int G = b * 256 + threadIdx.x;
        int row = G >> 5, c8 = G & 31;
        const float4* s = (const float4*)(z + (size_t)row * DIM + c8 * 8);
        float4 x = s[0], y = s[1];
        float v[8] = {x.x, x.y, x.z, x.w, y.x, y.y, y.z, y.w};
        half8 h;
        #pragma unroll
        for (int i = 0; i < 8; ++i) h[i] = (_Float16)v[i];
        int zblk = row >> 7, r = row & 127, kc = c8 >> 2, gk = c8 & 3;
        size_t o = ((size_t)((zblk * 8 + kc) * 4 + gk) * 128 + r) * 8;
        *(half8*)(zhp + o) = h;
    } else if (b < 4096) {                // ---- cb convert + fp64 cnorm: one wave per row
        int w = threadIdx.x >> 6, lane = threadIdx.x & 63;
        int row = (b - 2048) * 4 + w;
        float4 v = *(const float4*)(cb + (size_t)row * DIM + lane * 4);
        half4 h;
        h[0] = (_Float16)v.x; h[1] = (_Float16)v.y; h[2] = (_Float16)v.z; h[3] = (_Float16)v.w;
        int c8 = lane >> 1, pos = (lane & 1) * 4;
        int cblk = row >> 8, r = row & 255, kc = c8 >> 2, gk = c8 & 3;
        size_t o = ((size_t)((cblk * 8 + kc) * 4 + gk) * 256 + r) * 8 + pos;
        *(half4*)(chp + o) = h;
        double s = (double)v.x * v.x + (double)v.y * v.y + (double)v.z * v.z + (double)v.w * v.w;
        #pragma unroll
        for (int off = 32; off; off >>= 1) s += __shfl_down(s, off, 64);
        if (lane == 0) cnorm[row] = (float)s;
    } else {                              // ---- zero meanAcc: 8 floats per thread
        int g = (b - 4096) * 256 + threadIdx.x;
        float4 zero = {0.f, 0.f, 0.f, 0.f};
        float4* p = (float4*)(meanAcc + (size_t)g * 8);
        p[0] = zero; p[1] = zero;
    }
}

// ---------------- distance screen: LDS-free direct-global MFMA, top-2 per 256-code block ----------------
// block = 256 codes x 64 z, 4 waves; wave = 64 codes x 64 z (4i x 4j of 16x16x32_f16).
__global__ __launch_bounds__(256, 3) void dist_kernel(const _Float16* __restrict__ zhp,
                                                      const _Float16* __restrict__ chp,
                                                      const float* __restrict__ cnorm,
                                                      unsigned long long* __restrict__ cand) {
    __shared__ unsigned long long red[4][64][2];   // 4KB, epilogue only

    const int tid = threadIdx.x;
    const int w = tid >> 6, lane = tid & 63;
    const int c16 = lane & 15, g4 = lane >> 4;

    // XCD-bijective swizzle (8192 blocks, 8 XCDs): each XCD gets a contiguous
    // 32-wide z-chunk across all 32 code-blocks -> per-XCD L2 working set ~5MB.
    int wg = (blockIdx.x & 7) * 1024 + (blockIdx.x >> 3);
    int cbY = wg & 31;      // code block (256 codes)
    int zbX = wg >> 5;      // z block (64 rows)

    f32x4 acc[4][4];
    #pragma unroll
    for (int i = 0; i < 4; ++i)
        #pragma unroll
        for (int j = 0; j < 4; ++j) acc[i][j] = 0.0f;

    // chp halfs: cblk*65536 + kc*8192 + gk*2048 + r*8 ; r = w*64 + i*16 + c16
    // zhp halfs: zblk*32768 + kc*4096 + gk*1024 + r*8 ; r = (zbX&1)*64 + j*16 + c16
    const _Float16* Abase = chp + (size_t)cbY * 65536 + g4 * 2048 + (w * 64 + c16) * 8;
    const _Float16* Bbase = zhp + (size_t)(zbX >> 1) * 32768 + g4 * 1024 + ((zbX & 1) * 64 + c16) * 8;

    half8 a[4], b[4], an[4], bn[4];
    #pragma unroll
    for (int i = 0; i < 4; ++i) a[i] = *(const half8*)(Abase + i * 128);
    #pragma unroll
    for (int j = 0; j < 4; ++j) b[j] = *(const half8*)(Bbase + j * 128);

    #pragma unroll
    for (int kc = 0; kc < 8; ++kc) {
        if (kc < 7) {
            #pragma unroll
            for (int i = 0; i < 4; ++i) an[i] = *(const half8*)(Abase + (kc + 1) * 8192 + i * 128);
            #pragma unroll
            for (int j = 0; j < 4; ++j) bn[j] = *(const half8*)(Bbase + (kc + 1) * 4096 + j * 128);
        }
        #pragma unroll
        for (int i = 0; i < 4; ++i)
            #pragma unroll
            for (int j = 0; j < 4; ++j)
                acc[i][j] = __builtin_amdgcn_mfma_f32_16x16x32_f16(a[i], b[j], acc[i][j], 0, 0, 0);
        if (kc < 7) {
            #pragma unroll
            for (int i = 0; i < 4; ++i) a[i] = an[i];
            #pragma unroll
            for (int j = 0; j < 4; ++j) b[j] = bn[j];
        }
    }

    // hoisted cnorm for this thread's 16 codes
    float cn[4][4];
    #pragma unroll
    for (int i = 0; i < 4; ++i)
        #pragma unroll
        for (int reg = 0; reg < 4; ++reg)
            cn[i][reg] = cnorm[cbY * 256 + w * 64 + i * 16 + g4 * 4 + reg];

    // epilogue: top-2 per (z-col, 256-code block); C/D: col=lane&15 (z), row=(lane>>4)*4+reg (code)
    #pragma unroll
    for (int j = 0; j < 4; ++j) {
        unsigned long long b1 = ~0ull, b2 = ~0ull;
        #pragma unroll
        for (int i = 0; i < 4; ++i) {
            #pragma unroll
            for (int reg = 0; reg < 4; ++reg) {
                int code = cbY * 256 + w * 64 + i * 16 + g4 * 4 + reg;
                float d = fmaf(-2.0f, acc[i][j][reg], cn[i][reg]);
                unsigned u = __float_as_uint(d);
                u ^= ((int)u < 0) ? 0xFFFFFFFFu : 0x80000000u;   // order-preserving
                unsigned long long key = ((unsigned long long)u << 32) | (unsigned)code;
                if (key < b1) { b2 = b1; b1 = key; }
                else if (key < b2) { b2 = key; }
            }
        }
        #pragma unroll
        for (int off = 16; off <= 32; off <<= 1) {
            unsigned long long o1 = __shfl_xor(b1, off), o2 = __shfl_xor(b2, off);
            unsigned long long m1 = (b1 < o1) ? b1 : o1;
            unsigned long long hi = (b1 < o1) ? o1 : b1;
            unsigned long long m2 = (b2 < o2) ? b2 : o2;
            b1 = m1; b2 = (m2 < hi) ? m2 : hi;
        }
        if (lane < 16) { red[w][j * 16 + lane][0] = b1; red[w][j * 16 + lane][1] = b2; }
    }
    __syncthreads();
    if (tid < 64) {
        unsigned long long b1 = ~0ull, b2 = ~0ull;
        #pragma unroll
        for (int t = 0; t < 4; ++t) {
            unsigned long long o1 = red[t][tid][0], o2 = red[t][tid][1];
            unsigned long long m1 = (b1 < o1) ? b1 : o1;
            unsigned long long hi = (b1 < o1) ? o1 : b1;
            unsigned long long m2 = (b2 < o2) ? b2 : o2;
            b1 = m1; b2 = (m2 < hi) ? m2 : hi;
        }
        size_t base = (size_t)(zbX * 64 + tid) * 64 + cbY * 2;
        cand[base] = b1;
        cand[base + 1] = b2;
    }
}

__device__ inline float decode_key(unsigned e) {
    unsigned orig = (e & 0x80000000u) ? (e ^ 0x80000000u) : ~e;
    return __uint_as_float(orig);
}

// ---------------- rescore (fp64 within margin) + assign, fused ----------------
__global__ __launch_bounds__(256) void rescore_assign_kernel(const float* __restrict__ z,
                                                             const float* __restrict__ cb,
                                                             const unsigned long long* __restrict__ cand,
                                                             float* __restrict__ zq_out,
                                                             float* __restrict__ idx_out,
                                                             float* __restrict__ counts,
                                                             float* __restrict__ meanAcc,
                                                             float* __restrict__ lossPart) {
    __shared__ float lred[4];
    int w = threadIdx.x >> 6, lane = threadIdx.x & 63;
    int row = blockIdx.x * 4 + w;
    unsigned long long k64 = cand[(size_t)row * 64 + lane];
    unsigned long long m = k64;
    #pragma unroll
    for (int off = 32; off; off >>= 1) {
        unsigned long long o = __shfl_xor(m, off);
        if (o < m) m = o;
    }
    float fmin = decode_key((unsigned)(m >> 32));
    float f = decode_key((unsigned)(k64 >> 32));
    unsigned long long mask = __ballot(f <= fmin + 1.0f);

    float4 zv = *(const float4*)(z + (size_t)row * DIM + lane * 4);
    double bd = 1e300;
    int bc = 0x7fffffff;
    while (mask) {
        int src = __ffsll((unsigned long long)mask) - 1;
        mask &= mask - 1;
        int code = (int)(unsigned)__shfl(k64, src);
        float4 c4 = *(const float4*)(cb + (size_t)code * DIM + lane * 4);
        double d0 = (double)zv.x - c4.x, d1 = (double)zv.y - c4.y;
        double d2 = (double)zv.z - c4.z, d3 = (double)zv.w - c4.w;
        double s = d0 * d0 + d1 * d1 + d2 * d2 + d3 * d3;
        #pragma unroll
        for (int off = 32; off; off >>= 1) s += __shfl_xor(s, off);
        if (s < bd || (s == bd && code < bc)) { bd = s; bc = code; }
    }

    float4 cv = *(const float4*)(cb + (size_t)bc * DIM + lane * 4);
    *(float4*)(zq_out + (size_t)row * DIM + lane * 4) = cv;
    float d0 = zv.x - cv.x, d1 = zv.y - cv.y, d2 = zv.z - cv.z, d3 = zv.w - cv.w;
    float ls = d0 * d0 + d1 * d1 + d2 * d2 + d3 * d3;
    #pragma unroll
    for (int off = 32; off; off >>= 1) ls += __shfl_down(ls, off, 64);
    float* mp = meanAcc + (size_t)bc * DIM + lane * 4;
    atomicAdd(mp + 0, zv.x);
    atomicAdd(mp + 1, zv.y);
    atomicAdd(mp + 2, zv.z);
    atomicAdd(mp + 3, zv.w);
    if (lane == 0) {
        idx_out[row] = (float)bc;
        atomicAdd(counts + bc, 1.0f);
        lred[w] = ls;
    }
    __syncthreads();
    if (threadIdx.x == 0)
        lossPart[blockIdx.x] = lred[0] + lred[1] + lred[2] + lred[3];
}

// ---------------- count finalize + n + loss scalar ----------------
__global__ __launch_bounds__(1024) void count_final_kernel(const float* __restrict__ ema_count,
                                                           const float* __restrict__ counts,
                                                           float* __restrict__ newCount_out,
                                                           float* __restrict__ nOut,
                                                           const float* __restrict__ lossPart,
                                                           float* __restrict__ loss_out) {
    __shared__ float sred[1024];
    const float OMD = (float)(1.0 - 0.99);
    int tid = threadIdx.x;
    float s = 0.f;
    #pragma unroll
    for (int k = tid; k < K_CODES; k += 1024) {
        float nc = 0.99f * ema_count[k] + OMD * counts[k];
        newCount_out[k] = nc;
        s += nc;
    }
    sred[tid] = s;
    __syncthreads();
    for (int off = 512; off; off >>= 1) {
        if (tid < off) sred[tid] += sred[tid + off];
        __syncthreads();
    }
    if (tid == 0) nOut[0] = sred[0];
    __syncthreads();
    float L = lossPart[tid] + lossPart[tid + 1024] + lossPart[tid + 2048] + lossPart[tid + 3072];
    sred[tid] = L;
    __syncthreads();
    for (int off = 512; off; off >>= 1) {
        if (tid < off) sred[tid] += sred[tid + off];
        __syncthreads();
    }
    if (tid == 0) loss_out[0] = 1.25f * sred[0] / 4194304.0f;
}

// ---------------- mean finalize + new codebook ----------------
__global__ __launch_bounds__(256) void final_kernel(const float* __restrict__ ema_mean,
                                                    const float* __restrict__ meanAcc,
                                                    const float* __restrict__ newCount,
                                                    const float* __restrict__ nPtr,
                                                    float* __restrict__ newMean_out,
                                                    float* __restrict__ newCb_out) {
    const float OMD = (float)(1.0 - 0.99);
    int g = blockIdx.x * 256 + threadIdx.x;
    int k = g >> 6;
    int c4 = (g & 63) * 4;
    float n = nPtr[0];
    float nc = newCount[k];
    float cs = (nc + 1e-5f) / (n + (float)(K_CODES * 1e-5)) * n;
    size_t base = (size_t)k * DIM + c4;
    float4 em = *(const float4*)(ema_mean + base);
    float4 mm = *(const float4*)(meanAcc + base);
    float4 nm;
    nm.x = 0.99f * em.x + OMD * mm.x;
    nm.y = 0.99f * em.y + OMD * mm.y;
    nm.z = 0.99f * em.z + OMD * mm.z;
    nm.w = 0.99f * em.w + OMD * mm.w;
    *(float4*)(newMean_out + base) = nm;
    float4 cbv;
    cbv.x = nm.x / cs;
    cbv.y = nm.y / cs;
    cbv.z = nm.z / cs;
    cbv.w = nm.w / cs;
    *(float4*)(newCb_out + base) = cbv;
}

extern "C" void kernel_launch(void* const* d_in, const int* in_sizes, int n_in,
                              void* d_out, int out_size, void* d_ws, size_t ws_size,
                              hipStream_t stream) {
    const float* z         = (const float*)d_in[0];
    const float* cb        = (const float*)d_in[1];
    const float* ema_count = (const float*)d_in[2];
    const float* ema_mean  = (const float*)d_in[3];
    float* out = (float*)d_out;
    char* ws = (char*)d_ws;

    float* counts   = (float*)(ws + WS_COUNTS);
    float* cnorm    = (float*)(ws + WS_CNORM);
    float* lossPart = (float*)(ws + WS_LOSSP);
    float* nPtr     = (float*)(ws + WS_N);
    float* meanAcc  = (float*)(ws + WS_MEAN);

    _Float16* zhp = (_Float16*)(out + POFF_ZHP);
    _Float16* chp = (_Float16*)(out + POFF_CHP);
    unsigned long long* cand = (unsigned long long*)(out + POFF_CAND);

    hipMemsetAsync(ws, 0, WS_MEAN, stream);   // counts/cnorm/lossPart/n only

    prep_kernel<<<5120, 256, 0, stream>>>(z, cb, zhp, chp, cnorm, meanAcc);
    dist_kernel<<<8192, 256, 0, stream>>>(zhp, chp, cnorm, cand);
    rescore_assign_kernel<<<N_ROWS / 4, 256, 0, stream>>>(z, cb, cand, out + OFF_ZQ,
                                                          out + OFF_IDX, counts, meanAcc, lossPart);
    count_final_kernel<<<1, 1024, 0, stream>>>(ema_count, counts, out + OFF_CNT, nPtr,
                                               lossPart, out + OFF_LOSS);
    final_kernel<<<(K_CODES * DIM / 4) / 256, 256, 0, stream>>>(ema_mean, meanAcc,
                                                                out + OFF_CNT, nPtr,
                                                                out + OFF_MEAN, out + OFF_CB);
}